// Round 17
// baseline (408.965 us; speedup 1.0000x reference)
//
#include <hip/hip_runtime.h>

typedef unsigned short u16;
using bf16x8 = __attribute__((ext_vector_type(8))) __bf16;
using f32x4  = __attribute__((ext_vector_type(4))) float;
using s16x8  = __attribute__((ext_vector_type(8))) short;
using s16x4  = __attribute__((ext_vector_type(4))) short;

#define AS1 __attribute__((address_space(1)))
#define AS3 __attribute__((address_space(3)))

__device__ __forceinline__ void gload16(const u16* g, u16* l) {
  __builtin_amdgcn_global_load_lds((AS1 void*)(size_t)g, (AS3 void*)l, 16, 0, 0);
}

__device__ __forceinline__ u16 f2bf(float f) {
  unsigned u = __float_as_uint(f);
  u += 0x7fffu + ((u >> 16) & 1u);   // round-to-nearest-even
  return (u16)(u >> 16);
}
__device__ __forceinline__ float bf2f(u16 h) {
  return __uint_as_float(((unsigned)h) << 16);
}

// ================= merged prep: cast + 5 transposes + rope table =================
__device__ __forceinline__ void transpose_tile(const float* __restrict__ W,
                                               u16* __restrict__ WT,
                                               int K, int N, int nb, int kb,
                                               u16 (*tile)[72]) {
  const int t = threadIdx.x;
  const int rr = t >> 3;        // 0..31
  const int cc = (t & 7) * 8;   // 0..56
#pragma unroll
  for (int pass = 0; pass < 2; ++pass) {
    const float* src = W + (size_t)(kb + pass * 32 + rr) * N + nb + cc;
    float4 a = *reinterpret_cast<const float4*>(src);
    float4 b = *reinterpret_cast<const float4*>(src + 4);
    u16* tr = &tile[pass * 32 + rr][cc];
    tr[0] = f2bf(a.x); tr[1] = f2bf(a.y); tr[2] = f2bf(a.z); tr[3] = f2bf(a.w);
    tr[4] = f2bf(b.x); tr[5] = f2bf(b.y); tr[6] = f2bf(b.z); tr[7] = f2bf(b.w);
  }
  __syncthreads();
#pragma unroll
  for (int pass = 0; pass < 2; ++pass) {
    s16x8 v;
#pragma unroll
    for (int j = 0; j < 8; ++j) v[j] = (short)tile[cc + j][pass * 32 + rr];
    *reinterpret_cast<s16x8*>(WT + (size_t)(nb + pass * 32 + rr) * K + kb + cc) = v;
  }
}

__global__ __launch_bounds__(256) void prep_merged_kernel(
    const float* __restrict__ hs, u16* __restrict__ hs_bf,
    const float* __restrict__ Wqa, const float* __restrict__ Wkva, u16* __restrict__ WabT,
    const float* __restrict__ Wqb, u16* __restrict__ WqbT,
    const float* __restrict__ Wkvb, u16* __restrict__ WkvbT,
    const float* __restrict__ Wo, u16* __restrict__ WoT,
    float* __restrict__ cost, float* __restrict__ sint) {
  __shared__ u16 tile[64][72];
  const int bid = blockIdx.x, t = threadIdx.x;
  if (bid < 8192) {                       // cast hs -> bf16
    int i = (bid * 256 + t) * 4;
    float4 v = *reinterpret_cast<const float4*>(hs + i);
    s16x4 o;
    o[0] = (short)f2bf(v.x); o[1] = (short)f2bf(v.y);
    o[2] = (short)f2bf(v.z); o[3] = (short)f2bf(v.w);
    *reinterpret_cast<s16x4*>(hs_bf + i) = o;
  } else if (bid < 9728) {                // Wqa [4096][1536] -> WabT[0..1536)
    int r = bid - 8192;
    transpose_tile(Wqa, WabT, 4096, 1536, (r % 24) * 64, (r / 24) * 64, tile);
  } else if (bid < 10304) {               // Wkva [4096][576] -> WabT[1536..2112)
    int r = bid - 9728;
    transpose_tile(Wkva, WabT + (size_t)1536 * 4096, 4096, 576, (r % 9) * 64, (r / 9) * 64, tile);
  } else if (bid < 12608) {               // Wqb [1536][6144]
    int r = bid - 10304;
    transpose_tile(Wqb, WqbT, 1536, 6144, (r % 96) * 64, (r / 96) * 64, tile);
  } else if (bid < 13632) {               // Wkvb [512][8192]
    int r = bid - 12608;
    transpose_tile(Wkvb, WkvbT, 512, 8192, (r % 128) * 64, (r / 128) * 64, tile);
  } else if (bid < 17728) {               // Wo [4096][4096]
    int r = bid - 13632;
    transpose_tile(Wo, WoT, 4096, 4096, (r % 64) * 64, (r / 64) * 64, tile);
  } else {                                // rope table
    int idx = (bid - 17728) * 256 + t;    // 65536
    int pos = idx >> 5, j = idx & 31;
    float inv = __expf(-(float)j * (9.210340371976184f / 32.0f));
    float f = (float)pos * inv;
    cost[idx] = cosf(f);
    sint[idx] = sinf(f);
  }
}

// ================= merged rmsnorms =================
__global__ __launch_bounds__(256) void norms_merged_kernel(const u16* __restrict__ fused,
                                                           const float* __restrict__ qln,
                                                           const float* __restrict__ kvln,
                                                           u16* __restrict__ qan,
                                                           u16* __restrict__ cn) {
  const int bid = blockIdx.x, t = threadIdx.x;
  const int row = bid & 2047;
  const bool is_q = bid < 2048;
  const int R = is_q ? 1536 : 512;
  const u16* xr = fused + (size_t)row * 2112 + (is_q ? 0 : 1536);
  const float* w = is_q ? qln : kvln;
  u16* yr = (is_q ? qan + (size_t)row * 1536 : cn + (size_t)row * 512);
  float ss = 0.f;
  for (int i = t; i < R; i += 256) { float f = bf2f(xr[i]); ss += f * f; }
#pragma unroll
  for (int m = 32; m >= 1; m >>= 1) ss += __shfl_xor(ss, m);
  __shared__ float red[4];
  if ((t & 63) == 0) red[t >> 6] = ss;
  __syncthreads();
  float tot = red[0] + red[1] + red[2] + red[3];
  float r = rsqrtf(tot / (float)R + 1e-6f);
  for (int i = t; i < R; i += 256) yr[i] = f2bf(bf2f(xr[i]) * r * w[i]);
}

// ================= kf rope-only build (qf now fused into q-GEMM epilogue) =================
__global__ __launch_bounds__(256) void build_kf_rope_kernel(const u16* __restrict__ ckv,
                                                            const float* __restrict__ cost,
                                                            const float* __restrict__ sint,
                                                            u16* __restrict__ kf) {
  int o8 = (blockIdx.x * 256 + threadIdx.x) * 8;   // 32*2048*64 range
  int j0 = o8 & 63;
  int rest = o8 >> 6;
  int s = rest & 2047, h = rest >> 11;
  bool lo = j0 < 32;
  int jj0 = lo ? j0 : j0 - 32;
  const u16* crow = ckv + (size_t)s * 2112 + 512;
  s16x8 a = *reinterpret_cast<const s16x8*>(crow + 2 * jj0);
  s16x8 b = *reinterpret_cast<const s16x8*>(crow + 2 * jj0 + 8);
  float4 c0 = *reinterpret_cast<const float4*>(cost + s * 32 + jj0);
  float4 c1 = *reinterpret_cast<const float4*>(cost + s * 32 + jj0 + 4);
  float4 s0 = *reinterpret_cast<const float4*>(sint + s * 32 + jj0);
  float4 s1 = *reinterpret_cast<const float4*>(sint + s * 32 + jj0 + 4);
  float cs[8] = {c0.x, c0.y, c0.z, c0.w, c1.x, c1.y, c1.z, c1.w};
  float sn[8] = {s0.x, s0.y, s0.z, s0.w, s1.x, s1.y, s1.z, s1.w};
  s16x8 out;
#pragma unroll
  for (int j = 0; j < 8; ++j) {
    float x0 = bf2f((u16)((j < 4) ? a[2 * j] : b[2 * j - 8]));
    float x1 = bf2f((u16)((j < 4) ? a[2 * j + 1] : b[2 * j - 7]));
    float v = lo ? (x0 * cs[j] - x1 * sn[j]) : (x1 * cs[j] + x0 * sn[j]);
    out[j] = (short)f2bf(v);
  }
  *reinterpret_cast<s16x8*>(kf + ((size_t)h * 2048 + s) * 192 + 128 + j0) = out;
}

// ---------------- GEMM v3 body (128x128, for ragged fused1) ----------------
template <int EPI>
__device__ __forceinline__ void gemm_v3_body(const u16* __restrict__ A,
                                             const u16* __restrict__ BT,
                                             void* __restrict__ Cv,
                                             int M, int N, int K,
                                             int bx, int by, u16* S) {
  const int t0 = threadIdx.x;
  const int lane = t0 & 63, wave = t0 >> 6;
  const int wr = wave >> 1, wc = wave & 1;
  const int row0 = by * 128, col0 = bx * 128;
  const int lrow = lane & 15, lkg = lane >> 4;

  const int lp = lane ^ ((lane >> 3) & 3);
  const int srow_off = lp >> 2;
  const int skel = (lp & 3) * 8;
  const int c0 = wave * 2, c1 = c0 + 1;
  const int arow_c0 = row0 + c0 * 16 + srow_off;
  const int arow_c1 = row0 + c1 * 16 + srow_off;
  int brow_c0 = col0 + c0 * 16 + srow_off; if (brow_c0 > N - 1) brow_c0 = N - 1;
  int brow_c1 = col0 + c1 * 16 + srow_off; if (brow_c1 > N - 1) brow_c1 = N - 1;

  int aoff[4], boff[4];
#pragma unroll
  for (int m = 0; m < 4; ++m) {
    int r = wr * 64 + m * 16 + lrow;
    int off = r * 32 + lkg * 8;
    aoff[m] = off ^ ((off >> 3) & 0x18);
    r = wc * 64 + m * 16 + lrow;
    off = r * 32 + lkg * 8;
    boff[m] = off ^ ((off >> 3) & 0x18);
  }

  const int NT = K >> 5;

#pragma unroll
  for (int pt = 0; pt < 3; ++pt) {
    u16* ab = &S[pt * 8192];
    const int kb = pt * 32 + skel;
    gload16(A  + (size_t)arow_c0 * K + kb, ab + c0 * 512);
    gload16(A  + (size_t)arow_c1 * K + kb, ab + c1 * 512);
    gload16(BT + (size_t)brow_c0 * K + kb, ab + 4096 + c0 * 512);
    gload16(BT + (size_t)brow_c1 * K + kb, ab + 4096 + c1 * 512);
  }

  f32x4 acc[4][4];
#pragma unroll
  for (int m = 0; m < 4; ++m)
#pragma unroll
    for (int n = 0; n < 4; ++n) acc[m][n] = 0.f;

  for (int t = 0; t < NT; ++t) {
    if (t + 2 < NT)      asm volatile("s_waitcnt vmcnt(8)" ::: "memory");
    else if (t + 1 < NT) asm volatile("s_waitcnt vmcnt(4)" ::: "memory");
    else                 asm volatile("s_waitcnt vmcnt(0)" ::: "memory");
    __builtin_amdgcn_s_barrier();
    __builtin_amdgcn_sched_barrier(0);

    const u16* ab = &S[(t & 3) * 8192];
    bf16x8 af[4], bb[4];
#pragma unroll
    for (int m = 0; m < 4; ++m)
      af[m] = *reinterpret_cast<const bf16x8*>(ab + aoff[m]);
#pragma unroll
    for (int n = 0; n < 4; ++n)
      bb[n] = *reinterpret_cast<const bf16x8*>(ab + 4096 + boff[n]);

    if (t + 3 < NT) {
      u16* sb = &S[((t + 3) & 3) * 8192];
      const int kb = (t + 3) * 32 + skel;
      gload16(A  + (size_t)arow_c0 * K + kb, sb + c0 * 512);
      gload16(A  + (size_t)arow_c1 * K + kb, sb + c1 * 512);
      gload16(BT + (size_t)brow_c0 * K + kb, sb + 4096 + c0 * 512);
      gload16(BT + (size_t)brow_c1 * K + kb, sb + 4096 + c1 * 512);
    }

    __builtin_amdgcn_s_setprio(1);
#pragma unroll
    for (int m = 0; m < 4; ++m)
#pragma unroll
      for (int n = 0; n < 4; ++n)
        acc[m][n] = __builtin_amdgcn_mfma_f32_16x16x32_bf16(af[m], bb[n], acc[m][n], 0, 0, 0);
    __builtin_amdgcn_s_setprio(0);
  }

#pragma unroll
  for (int m = 0; m < 4; ++m) {
#pragma unroll
    for (int n = 0; n < 4; ++n) {
      int col = col0 + wc * 64 + n * 16 + lrow;
      int row = row0 + wr * 64 + m * 16 + lkg * 4;
      if (col < N) {
#pragma unroll
        for (int i = 0; i < 4; ++i) {
          size_t idx = (size_t)(row + i) * N + col;
          if (EPI == 1) ((u16*)Cv)[idx] = f2bf(acc[m][n][i]);
          else          ((float*)Cv)[idx] = acc[m][n][i];
        }
      }
    }
  }
}

template <int EPI>
__global__ __launch_bounds__(256) void gemm_v3_kernel(const u16* __restrict__ A,
                                                      const u16* __restrict__ BT,
                                                      void* __restrict__ Cv,
                                                      int M, int N, int K) {
  __shared__ __align__(16) u16 S[4 * 8192];
  gemm_v3_body<EPI>(A, BT, Cv, M, N, K, blockIdx.x, blockIdx.y, S);
}

// ---------------- GEMM v4 body: 128(M)x256(N) tile, per-wave 64x128 ----------------
// EPI: 0 = f32 C, 1 = bf16 C, 2 = MLA-kv split (kf nope + vT direct),
//      3 = MLA-q: RoPE+scale fused, writes qf [h][s][192] directly.
//      RoPE partner value comes from __shfl_xor(acc,1) (cols 2jj/2jj+1 differ
//      only in lrow bit 0); each 16-col fragment is wholly nope or rope.
template <int EPI>
__device__ __forceinline__ void gemm_v4_body(const u16* __restrict__ A,
                                             const u16* __restrict__ BT,
                                             void* __restrict__ Cv,
                                             void* __restrict__ Cv2,
                                             const float* __restrict__ cost,
                                             const float* __restrict__ sint,
                                             int M, int N, int K,
                                             int bx, int by, u16* S) {
  const int t0 = threadIdx.x;
  const int lane = t0 & 63, wave = t0 >> 6;
  const int wr = wave >> 1, wc = wave & 1;
  const int row0 = by * 128, col0 = bx * 256;
  const int lrow = lane & 15, lkg = lane >> 4;

  const int lp = lane ^ ((lane >> 3) & 3);
  const int srow_off = lp >> 2;
  const int skel = (lp & 3) * 8;

  const int ac0 = wave * 2, ac1 = ac0 + 1;
  const int arow_0 = row0 + ac0 * 16 + srow_off;
  const int arow_1 = row0 + ac1 * 16 + srow_off;
  int brow[4];
#pragma unroll
  for (int j = 0; j < 4; ++j) {
    int r = col0 + (wave * 4 + j) * 16 + srow_off;
    brow[j] = (r > N - 1) ? (N - 1) : r;
  }

  int aoff[4], boff[8];
#pragma unroll
  for (int m = 0; m < 4; ++m) {
    int r = wr * 64 + m * 16 + lrow;
    int off = r * 32 + lkg * 8;
    aoff[m] = off ^ ((off >> 3) & 0x18);
  }
#pragma unroll
  for (int n = 0; n < 8; ++n) {
    int r = wc * 128 + n * 16 + lrow;
    int off = r * 32 + lkg * 8;
    boff[n] = off ^ ((off >> 3) & 0x18);
  }

  const int NT = K >> 5;

#pragma unroll
  for (int pt = 0; pt < 2; ++pt) {
    u16* sb = &S[pt * 12288];
    const int kb = pt * 32 + skel;
    gload16(A + (size_t)arow_0 * K + kb, sb + ac0 * 512);
    gload16(A + (size_t)arow_1 * K + kb, sb + ac1 * 512);
#pragma unroll
    for (int j = 0; j < 4; ++j)
      gload16(BT + (size_t)brow[j] * K + kb, sb + 4096 + (wave * 4 + j) * 512);
  }

  f32x4 acc[4][8];
#pragma unroll
  for (int m = 0; m < 4; ++m)
#pragma unroll
    for (int n = 0; n < 8; ++n) acc[m][n] = 0.f;

  int bufr = 0, bufw = 2;
  for (int t = 0; t < NT; ++t) {
    if (t + 2 < NT) {
      u16* sb = &S[bufw * 12288];
      const int kb = (t + 2) * 32 + skel;
      gload16(A + (size_t)arow_0 * K + kb, sb + ac0 * 512);
      gload16(A + (size_t)arow_1 * K + kb, sb + ac1 * 512);
#pragma unroll
      for (int j = 0; j < 4; ++j)
        gload16(BT + (size_t)brow[j] * K + kb, sb + 4096 + (wave * 4 + j) * 512);
      bufw = (bufw + 1 == 3) ? 0 : bufw + 1;
      asm volatile("s_waitcnt vmcnt(12)" ::: "memory");
    } else if (t + 1 < NT) {
      asm volatile("s_waitcnt vmcnt(6)" ::: "memory");
    } else {
      asm volatile("s_waitcnt vmcnt(0)" ::: "memory");
    }
    __builtin_amdgcn_s_barrier();
    __builtin_amdgcn_sched_barrier(0);

    const u16* ab = &S[bufr * 12288];
    bufr = (bufr + 1 == 3) ? 0 : bufr + 1;
    bf16x8 af[4];
#pragma unroll
    for (int m = 0; m < 4; ++m)
      af[m] = *reinterpret_cast<const bf16x8*>(ab + aoff[m]);

    __builtin_amdgcn_s_setprio(1);
#pragma unroll
    for (int n = 0; n < 8; ++n) {
      bf16x8 bbn = *reinterpret_cast<const bf16x8*>(ab + 4096 + boff[n]);
#pragma unroll
      for (int m = 0; m < 4; ++m)
        acc[m][n] = __builtin_amdgcn_mfma_f32_16x16x32_bf16(af[m], bbn, acc[m][n], 0, 0, 0);
    }
    __builtin_amdgcn_s_setprio(0);
  }

  const float scale = 0.07216878364870323f;  // 192^-0.5 (EPI=3)
#pragma unroll
  for (int m = 0; m < 4; ++m) {
#pragma unroll
    for (int n = 0; n < 8; ++n) {
      int col = col0 + wc * 128 + n * 16 + lrow;
      int row = row0 + wr * 64 + m * 16 + lkg * 4;
      if (EPI == 2) {
        int d = col & 255, hh = col >> 8;
        if (d < 128) {
          u16* dst = (u16*)Cv + ((size_t)hh * 2048 + row) * 192 + d;
#pragma unroll
          for (int i = 0; i < 4; ++i) dst[(size_t)i * 192] = f2bf(acc[m][n][i]);
        } else {
          s16x4 v;
#pragma unroll
          for (int i = 0; i < 4; ++i) v[i] = (short)f2bf(acc[m][n][i]);
          *reinterpret_cast<s16x4*>((u16*)Cv2 + ((size_t)hh * 128 + (d - 128)) * 2048 + row) = v;
        }
      } else if (EPI == 3) {
        int hh = col / 192, d = col - hh * 192;
        u16* base = (u16*)Cv + (size_t)hh * 2048 * 192;
        if (d < 128) {
#pragma unroll
          for (int i = 0; i < 4; ++i)
            base[(size_t)(row + i) * 192 + d] = f2bf(acc[m][n][i] * scale);
        } else {
          int jj = (d - 128) >> 1;
          bool even = ((d & 1) == 0);
          int dout = even ? (128 + jj) : (160 + jj);
#pragma unroll
          for (int i = 0; i < 4; ++i) {
            float self = acc[m][n][i];
            float partner = __shfl_xor(self, 1);
            int s = row + i;
            float c = cost[s * 32 + jj], sn = sint[s * 32 + jj];
            float v = even ? (self * c - partner * sn) : (self * c + partner * sn);
            base[(size_t)s * 192 + dout] = f2bf(v * scale);
          }
        }
      } else if (col < N) {
#pragma unroll
        for (int i = 0; i < 4; ++i) {
          size_t idx = (size_t)(row + i) * N + col;
          if (EPI == 1) ((u16*)Cv)[idx] = f2bf(acc[m][n][i]);
          else          ((float*)Cv)[idx] = acc[m][n][i];
        }
      }
    }
  }
}

template <int EPI>
__global__ __launch_bounds__(256, 2) void gemm_v4_kernel(const u16* __restrict__ A,
                                                         const u16* __restrict__ BT,
                                                         void* __restrict__ Cv,
                                                         void* __restrict__ Cv2,
                                                         int M, int N, int K) {
  __shared__ __align__(16) u16 S[3 * 12288];
  gemm_v4_body<EPI>(A, BT, Cv, Cv2, nullptr, nullptr, M, N, K, blockIdx.x, blockIdx.y, S);
}

// merged q-GEMM (z=0, EPI=3 RoPE-fused -> qf) + kv-GEMM (z=1, EPI=2 -> kf+vT)
__global__ __launch_bounds__(256, 2) void gemm_qkv_kernel(const u16* __restrict__ qan,
                                                          const u16* __restrict__ WqbT,
                                                          u16* __restrict__ qfb,
                                                          const u16* __restrict__ cn,
                                                          const u16* __restrict__ WkvbT,
                                                          u16* __restrict__ kfb,
                                                          u16* __restrict__ vTb,
                                                          const float* __restrict__ cost,
                                                          const float* __restrict__ sint) {
  __shared__ __align__(16) u16 S[3 * 12288];
  if (blockIdx.z == 0) {
    if (blockIdx.x >= 24) return;
    gemm_v4_body<3>(qan, WqbT, qfb, nullptr, cost, sint, 2048, 6144, 1536, blockIdx.x, blockIdx.y, S);
  } else {
    gemm_v4_body<2>(cn, WkvbT, kfb, vTb, nullptr, nullptr, 2048, 8192, 512, blockIdx.x, blockIdx.y, S);
  }
}

// ---------------- causal flash attention v7 (r16: 122us; KVBLK=64, K dbuf + counted vmcnt) ----------------
__global__ __launch_bounds__(256) void mla_attn_kernel(const u16* __restrict__ qf,
                                                       const u16* __restrict__ kf,
                                                       const u16* __restrict__ vT,
                                                       u16* __restrict__ o) {
  const int h = blockIdx.x, pair = blockIdx.y;
  const int t = threadIdx.x, wave = t >> 6, lane = t & 63;
  const int lrow = lane & 15, lkg = lane >> 4;
  __shared__ __align__(16) u16 Kt[2][24 * 512];
  __shared__ __align__(16) u16 Vt[16 * 512];
  __shared__ __align__(16) u16 Pl[4][16][72];

  const u16* ksrc0 = kf + ((size_t)h * 2048 + wave * 16 + lrow) * 192 + lkg * 8;
  const u16* vsrc0 = vT + ((size_t)h * 128 + wave * 32 + lrow) * 2048 + lkg * 8;

  for (int qq = 0; qq < 2; ++qq) {
    const int qb = qq ? (31 - pair) : pair;
    const int qbase = qb * 64 + wave * 16;

    bf16x8 qfr[6];
    const u16* qrow_ptr = qf + ((size_t)h * 2048 + qbase + lrow) * 192;
#pragma unroll
    for (int kk = 0; kk < 6; ++kk)
      qfr[kk] = *reinterpret_cast<const bf16x8*>(qrow_ptr + kk * 32 + lkg * 8);

    f32x4 acc_o[8];
#pragma unroll
    for (int f = 0; f < 8; ++f) acc_o[f] = 0.f;
    float m_run[4], l_par[4];
#pragma unroll
    for (int i = 0; i < 4; ++i) { m_run[i] = -1e30f; l_par[i] = 0.f; }

    const int nt = qb + 1;   // KV tiles of 64

    // prologue: K(0) -> Kt[0], V(0) -> Vt
#pragma unroll
    for (int kk = 0; kk < 6; ++kk)
      gload16(ksrc0 + kk * 32, &Kt[0][(wave * 6 + kk) * 512]);
#pragma unroll
    for (int j = 0; j < 4; ++j) {
      int fo = (j >> 1), ck = j & 1;
      gload16(vsrc0 + (size_t)fo * 16 * 2048 + ck * 32,
              &Vt[((wave * 2 + fo) * 2 + ck) * 512]);
    }

    for (int it = 0; it < nt; ++it) {
      const int kt = it * 64;
      if (it + 1 < nt) {
        const u16* ks = ksrc0 + (size_t)(kt + 64) * 192;
        u16* kd = &Kt[(it + 1) & 1][0];
#pragma unroll
        for (int kk = 0; kk < 6; ++kk)
          gload16(ks + kk * 32, kd + (wave * 6 + kk) * 512);
        asm volatile("s_waitcnt vmcnt(6)" ::: "memory");
      } else {
        asm volatile("s_waitcnt vmcnt(0)" ::: "memory");
      }
      __builtin_amdgcn_s_barrier();
      __builtin_amdgcn_sched_barrier(0);

      const u16* Kb = &Kt[it & 1][0];
      f32x4 sv[4];
#pragma unroll
      for (int cg = 0; cg < 4; ++cg) sv[cg] = 0.f;
#pragma unroll
      for (int cg = 0; cg < 4; ++cg)
#pragma unroll
        for (int kk = 0; kk < 6; ++kk) {
          bf16x8 kfr = *reinterpret_cast<const bf16x8*>(&Kb[(cg * 6 + kk) * 512 + lane * 8]);
          sv[cg] = __builtin_amdgcn_mfma_f32_16x16x32_bf16(qfr[kk], kfr, sv[cg], 0, 0, 0);
        }

      const int qrow_b = qbase + lkg * 4;
      if (it + 1 == nt) {
#pragma unroll
        for (int cg = 0; cg < 4; ++cg) {
          int kvcol = kt + cg * 16 + lrow;
#pragma unroll
          for (int i = 0; i < 4; ++i)
            if (kvcol > qrow_b + i) sv[cg][i] = -__builtin_inff();
        }
      }
      float tmax[4];
#pragma unroll
      for (int i = 0; i < 4; ++i)
        tmax[i] = fmaxf(fmaxf(sv[0][i], sv[1][i]), fmaxf(sv[2][i], sv[3][i]));
#pragma unroll
      for (int m = 8; m >= 1; m >>= 1)
#pragma unroll
        for (int i = 0; i < 4; ++i) tmax[i] = fmaxf(tmax[i], __shfl_xor(tmax[i], m));
      int need = 0;
#pragma unroll
      for (int i = 0; i < 4; ++i) need |= (tmax[i] > m_run[i] + 8.f) ? 1 : 0;
      if (__any(need)) {
#pragma unroll
        for (int i = 0; i < 4; ++i) {
          float mnew = fmaxf(m_run[i], tmax[i]);
          float alpha = __expf(m_run[i] - mnew);
          m_run[i] = mnew;
          l_par[i] *= alpha;
#pragma unroll
          for (int f = 0; f < 8; ++f) acc_o[f][i] *= alpha;
        }
      }
#pragma unroll
      for (int i = 0; i < 4; ++i) {
#pragma unroll
        for (int cg = 0; cg < 4; ++cg) sv[cg][i] = __expf(sv[cg][i] - m_run[i]);
        l_par[i] += (sv[0][i] + sv[1][i]) + (sv[2][i] + sv[3][i]);
      }
#pragma unroll
      for (int cg = 0; cg < 4; ++cg)
#pragma unroll
        for (int i = 0; i < 4; ++i)
          Pl[wave][lkg * 4 + i][cg * 16 + lrow] = f2bf(sv[cg][i]);
#pragma unroll
      for (int ck = 0; ck < 2; ++ck) {
        bf16x8 pf = *reinterpret_cast<const bf16x8*>(&Pl[wave][lrow][ck * 32 + lkg * 8]);
#pragma unroll
        for (int f = 0; f < 8; ++f) {
          bf16x8 vfr = *reinterpret_cast<const bf16x8*>(&Vt[(f * 2 + ck) * 512 + lane * 8]);
          acc_o[f] = __builtin_amdgcn_mfma_f32_16x16x32_bf16(pf, vfr, acc_o[f], 0, 0, 0);
        }
      }
      __builtin_amdgcn_sched_barrier(0);
      __builtin_amdgcn_s_barrier();
      if (it + 1 < nt) {
        const u16* vs = vsrc0 + kt + 64;
#pragma unroll
        for (int j = 0; j < 4; ++j) {
          int fo = (j >> 1), ck = j & 1;
          gload16(vs + (size_t)fo * 16 * 2048 + ck * 32,
                  &Vt[((wave * 2 + fo) * 2 + ck) * 512]);
        }
      }
    }
#pragma unroll
    for (int i = 0; i < 4; ++i)
#pragma unroll
      for (int m = 8; m >= 1; m >>= 1) l_par[i] += __shfl_xor(l_par[i], m);
#pragma unroll
    for (int f = 0; f < 8; ++f)
#pragma unroll
      for (int i = 0; i < 4; ++i) {
        int row = qbase + lkg * 4 + i;
        int col = h * 128 + f * 16 + lrow;
        o[(size_t)row * 4096 + col] = f2bf(acc_o[f][i] / l_par[i]);
      }
  }
}

// ---------------------------------------------------------------
extern "C" void kernel_launch(void* const* d_in, const int* in_sizes, int n_in,
                              void* d_out, int out_size, void* d_ws, size_t ws_size,
                              hipStream_t stream) {
  (void)in_sizes; (void)n_in; (void)out_size; (void)ws_size;
  const float* hs   = (const float*)d_in[0];
  const float* Wqa  = (const float*)d_in[1];
  const float* qln  = (const float*)d_in[2];
  const float* Wqb  = (const float*)d_in[3];
  const float* Wkva = (const float*)d_in[4];
  const float* kvln = (const float*)d_in[5];
  const float* Wkvb = (const float*)d_in[6];
  const float* Wo   = (const float*)d_in[7];
  float* out = (float*)d_out;

  char* p = (char*)d_ws;
  size_t off = 0;
  auto carve = [&](size_t bytes) {
    char* r = p + off;
    off += (bytes + 255) & ~(size_t)255;
    return r;
  };
  u16* hs_bf = (u16*)carve((size_t)2048 * 4096 * 2);
  u16* WabT  = (u16*)carve((size_t)2112 * 4096 * 2);   // [0..1535]=WqaT, [1536..2111]=WkvaT
  u16* WqbT  = (u16*)carve((size_t)6144 * 1536 * 2);
  u16* WkvbT = (u16*)carve((size_t)8192 * 512 * 2);
  u16* WoT   = (u16*)carve((size_t)4096 * 4096 * 2);
  u16* fused = (u16*)carve((size_t)2048 * 2112 * 2);   // [qa | ckv] per row
  u16* qan   = (u16*)carve((size_t)2048 * 1536 * 2);
  u16* cn    = (u16*)carve((size_t)2048 * 512 * 2);
  u16* qfb   = (u16*)carve((size_t)32 * 2048 * 192 * 2);
  u16* kfb   = (u16*)carve((size_t)32 * 2048 * 192 * 2);
  u16* vTb   = (u16*)carve((size_t)32 * 128 * 2048 * 2);
  u16* ob    = (u16*)carve((size_t)2048 * 4096 * 2);
  float* cost = (float*)carve((size_t)65536 * 4);
  float* sint = (float*)carve((size_t)65536 * 4);

  // --- merged prep: cast + 5 transposes + rope table (1 launch) ---
  prep_merged_kernel<<<17984, 256, 0, stream>>>(hs, hs_bf, Wqa, Wkva, WabT,
                                                Wqb, WqbT, Wkvb, WkvbT, Wo, WoT,
                                                cost, sint);

  // --- fused first-stage GEMM (ragged N=2112 -> v3) ---
  gemm_v3_kernel<1><<<dim3(17, 16), 256, 0, stream>>>(hs_bf, WabT, fused, 2048, 2112, 4096);

  // --- merged norms (1 launch) ---
  norms_merged_kernel<<<4096, 256, 0, stream>>>(fused, qln, kvln, qan, cn);

  // --- merged q+kv second-stage GEMMs (v4; q writes qf w/ fused RoPE, kv writes kf+vT) ---
  gemm_qkv_kernel<<<dim3(32, 16, 2), 256, 0, stream>>>(qan, WqbT, qfb, cn, WkvbT, kfb, vTb,
                                                       cost, sint);

  // --- kf RoPE build only (qf now fused into GEMM) ---
  build_kf_rope_kernel<<<2048, 256, 0, stream>>>(fused + 1536, cost, sint, kfb);

  // --- attention v7 (512 blocks, 2/CU, KVBLK=64, K dbuf + counted vmcnt) ---
  mla_attn_kernel<<<dim3(32, 16), 256, 0, stream>>>(qfb, kfb, vTb, ob);

  // --- output projection (v4: 16x16 = 256 blocks, exact 1/CU) ---
  gemm_v4_kernel<0><<<dim3(16, 16), 256, 0, stream>>>(ob, WoT, out, nullptr, 2048, 4096, 4096);
}

// Round 18
// 392.767 us; speedup vs baseline: 1.0412x; 1.0412x over previous
//
#include <hip/hip_runtime.h>

typedef unsigned short u16;
using bf16x8 = __attribute__((ext_vector_type(8))) __bf16;
using f32x4  = __attribute__((ext_vector_type(4))) float;
using s16x8  = __attribute__((ext_vector_type(8))) short;
using s16x4  = __attribute__((ext_vector_type(4))) short;

#define AS1 __attribute__((address_space(1)))
#define AS3 __attribute__((address_space(3)))

__device__ __forceinline__ void gload16(const u16* g, u16* l) {
  __builtin_amdgcn_global_load_lds((AS1 void*)(size_t)g, (AS3 void*)l, 16, 0, 0);
}

__device__ __forceinline__ u16 f2bf(float f) {
  unsigned u = __float_as_uint(f);
  u += 0x7fffu + ((u >> 16) & 1u);   // round-to-nearest-even
  return (u16)(u >> 16);
}
__device__ __forceinline__ float bf2f(u16 h) {
  return __uint_as_float(((unsigned)h) << 16);
}

// ================= merged prep: cast + 5 transposes + rope table =================
__device__ __forceinline__ void transpose_tile(const float* __restrict__ W,
                                               u16* __restrict__ WT,
                                               int K, int N, int nb, int kb,
                                               u16 (*tile)[72]) {
  const int t = threadIdx.x;
  const int rr = t >> 3;        // 0..31
  const int cc = (t & 7) * 8;   // 0..56
#pragma unroll
  for (int pass = 0; pass < 2; ++pass) {
    const float* src = W + (size_t)(kb + pass * 32 + rr) * N + nb + cc;
    float4 a = *reinterpret_cast<const float4*>(src);
    float4 b = *reinterpret_cast<const float4*>(src + 4);
    u16* tr = &tile[pass * 32 + rr][cc];
    tr[0] = f2bf(a.x); tr[1] = f2bf(a.y); tr[2] = f2bf(a.z); tr[3] = f2bf(a.w);
    tr[4] = f2bf(b.x); tr[5] = f2bf(b.y); tr[6] = f2bf(b.z); tr[7] = f2bf(b.w);
  }
  __syncthreads();
#pragma unroll
  for (int pass = 0; pass < 2; ++pass) {
    s16x8 v;
#pragma unroll
    for (int j = 0; j < 8; ++j) v[j] = (short)tile[cc + j][pass * 32 + rr];
    *reinterpret_cast<s16x8*>(WT + (size_t)(nb + pass * 32 + rr) * K + kb + cc) = v;
  }
}

__global__ __launch_bounds__(256) void prep_merged_kernel(
    const float* __restrict__ hs, u16* __restrict__ hs_bf,
    const float* __restrict__ Wqa, const float* __restrict__ Wkva, u16* __restrict__ WabT,
    const float* __restrict__ Wqb, u16* __restrict__ WqbT,
    const float* __restrict__ Wkvb, u16* __restrict__ WkvbT,
    const float* __restrict__ Wo, u16* __restrict__ WoT,
    float* __restrict__ cost, float* __restrict__ sint) {
  __shared__ u16 tile[64][72];
  const int bid = blockIdx.x, t = threadIdx.x;
  if (bid < 8192) {                       // cast hs -> bf16
    int i = (bid * 256 + t) * 4;
    float4 v = *reinterpret_cast<const float4*>(hs + i);
    s16x4 o;
    o[0] = (short)f2bf(v.x); o[1] = (short)f2bf(v.y);
    o[2] = (short)f2bf(v.z); o[3] = (short)f2bf(v.w);
    *reinterpret_cast<s16x4*>(hs_bf + i) = o;
  } else if (bid < 9728) {                // Wqa [4096][1536] -> WabT[0..1536)
    int r = bid - 8192;
    transpose_tile(Wqa, WabT, 4096, 1536, (r % 24) * 64, (r / 24) * 64, tile);
  } else if (bid < 10304) {               // Wkva [4096][576] -> WabT[1536..2112)
    int r = bid - 9728;
    transpose_tile(Wkva, WabT + (size_t)1536 * 4096, 4096, 576, (r % 9) * 64, (r / 9) * 64, tile);
  } else if (bid < 12608) {               // Wqb [1536][6144]
    int r = bid - 10304;
    transpose_tile(Wqb, WqbT, 1536, 6144, (r % 96) * 64, (r / 96) * 64, tile);
  } else if (bid < 13632) {               // Wkvb [512][8192]
    int r = bid - 12608;
    transpose_tile(Wkvb, WkvbT, 512, 8192, (r % 128) * 64, (r / 128) * 64, tile);
  } else if (bid < 17728) {               // Wo [4096][4096]
    int r = bid - 13632;
    transpose_tile(Wo, WoT, 4096, 4096, (r % 64) * 64, (r / 64) * 64, tile);
  } else {                                // rope table
    int idx = (bid - 17728) * 256 + t;    // 65536
    int pos = idx >> 5, j = idx & 31;
    float inv = __expf(-(float)j * (9.210340371976184f / 32.0f));
    float f = (float)pos * inv;
    cost[idx] = cosf(f);
    sint[idx] = sinf(f);
  }
}

// ================= merged rmsnorms =================
__global__ __launch_bounds__(256) void norms_merged_kernel(const u16* __restrict__ fused,
                                                           const float* __restrict__ qln,
                                                           const float* __restrict__ kvln,
                                                           u16* __restrict__ qan,
                                                           u16* __restrict__ cn) {
  const int bid = blockIdx.x, t = threadIdx.x;
  const int row = bid & 2047;
  const bool is_q = bid < 2048;
  const int R = is_q ? 1536 : 512;
  const u16* xr = fused + (size_t)row * 2112 + (is_q ? 0 : 1536);
  const float* w = is_q ? qln : kvln;
  u16* yr = (is_q ? qan + (size_t)row * 1536 : cn + (size_t)row * 512);
  float ss = 0.f;
  for (int i = t; i < R; i += 256) { float f = bf2f(xr[i]); ss += f * f; }
#pragma unroll
  for (int m = 32; m >= 1; m >>= 1) ss += __shfl_xor(ss, m);
  __shared__ float red[4];
  if ((t & 63) == 0) red[t >> 6] = ss;
  __syncthreads();
  float tot = red[0] + red[1] + red[2] + red[3];
  float r = rsqrtf(tot / (float)R + 1e-6f);
  for (int i = t; i < R; i += 256) yr[i] = f2bf(bf2f(xr[i]) * r * w[i]);
}

// ================= merged builds: qf (RoPE+scale) + kf rope-only =================
__global__ __launch_bounds__(256) void builds_merged_kernel(const u16* __restrict__ q,
                                                            const u16* __restrict__ ckv,
                                                            const float* __restrict__ cost,
                                                            const float* __restrict__ sint,
                                                            u16* __restrict__ qf,
                                                            u16* __restrict__ kf) {
  const int bid = blockIdx.x, t = threadIdx.x;
  if (bid < 6144) {
    int o8 = (bid * 256 + t) * 8;
    const float scale = 0.07216878364870323f;  // 192^-0.5 folded into q
    int c = (o8 % 192) >> 3;
    int rest = o8 / 192;
    int s = rest & 2047, h = rest >> 11;
    const u16* qrow = q + ((size_t)s * 32 + h) * 192;
    s16x8 out;
    if (c < 16) {
      s16x8 v = *reinterpret_cast<const s16x8*>(qrow + c * 8);
#pragma unroll
      for (int j = 0; j < 8; ++j) out[j] = (short)f2bf(bf2f((u16)v[j]) * scale);
    } else {
      int j0 = c * 8 - 128;
      bool lo = j0 < 32;
      int jj0 = lo ? j0 : j0 - 32;
      s16x8 a = *reinterpret_cast<const s16x8*>(qrow + 128 + 2 * jj0);
      s16x8 b = *reinterpret_cast<const s16x8*>(qrow + 128 + 2 * jj0 + 8);
      float4 c0 = *reinterpret_cast<const float4*>(cost + s * 32 + jj0);
      float4 c1 = *reinterpret_cast<const float4*>(cost + s * 32 + jj0 + 4);
      float4 s0 = *reinterpret_cast<const float4*>(sint + s * 32 + jj0);
      float4 s1 = *reinterpret_cast<const float4*>(sint + s * 32 + jj0 + 4);
      float cs[8] = {c0.x, c0.y, c0.z, c0.w, c1.x, c1.y, c1.z, c1.w};
      float sn[8] = {s0.x, s0.y, s0.z, s0.w, s1.x, s1.y, s1.z, s1.w};
#pragma unroll
      for (int j = 0; j < 8; ++j) {
        float x0 = bf2f((u16)((j < 4) ? a[2 * j] : b[2 * j - 8]));
        float x1 = bf2f((u16)((j < 4) ? a[2 * j + 1] : b[2 * j - 7]));
        float v = lo ? (x0 * cs[j] - x1 * sn[j]) : (x1 * cs[j] + x0 * sn[j]);
        out[j] = (short)f2bf(v * scale);
      }
    }
    *reinterpret_cast<s16x8*>(qf + o8) = out;
  } else {
    int o8 = ((bid - 6144) * 256 + t) * 8;   // 32*2048*64 range
    int j0 = o8 & 63;
    int rest = o8 >> 6;
    int s = rest & 2047, h = rest >> 11;
    bool lo = j0 < 32;
    int jj0 = lo ? j0 : j0 - 32;
    const u16* crow = ckv + (size_t)s * 2112 + 512;
    s16x8 a = *reinterpret_cast<const s16x8*>(crow + 2 * jj0);
    s16x8 b = *reinterpret_cast<const s16x8*>(crow + 2 * jj0 + 8);
    float4 c0 = *reinterpret_cast<const float4*>(cost + s * 32 + jj0);
    float4 c1 = *reinterpret_cast<const float4*>(cost + s * 32 + jj0 + 4);
    float4 s0 = *reinterpret_cast<const float4*>(sint + s * 32 + jj0);
    float4 s1 = *reinterpret_cast<const float4*>(sint + s * 32 + jj0 + 4);
    float cs[8] = {c0.x, c0.y, c0.z, c0.w, c1.x, c1.y, c1.z, c1.w};
    float sn[8] = {s0.x, s0.y, s0.z, s0.w, s1.x, s1.y, s1.z, s1.w};
    s16x8 out;
#pragma unroll
    for (int j = 0; j < 8; ++j) {
      float x0 = bf2f((u16)((j < 4) ? a[2 * j] : b[2 * j - 8]));
      float x1 = bf2f((u16)((j < 4) ? a[2 * j + 1] : b[2 * j - 7]));
      float v = lo ? (x0 * cs[j] - x1 * sn[j]) : (x1 * cs[j] + x0 * sn[j]);
      out[j] = (short)f2bf(v);
    }
    *reinterpret_cast<s16x8*>(kf + ((size_t)h * 2048 + s) * 192 + 128 + j0) = out;
  }
}

// ---------------- GEMM v3 body (128x128, for ragged fused1) ----------------
template <int EPI>
__device__ __forceinline__ void gemm_v3_body(const u16* __restrict__ A,
                                             const u16* __restrict__ BT,
                                             void* __restrict__ Cv,
                                             void* __restrict__ Cv2,
                                             int M, int N, int K,
                                             int bx, int by, u16* S) {
  const int t0 = threadIdx.x;
  const int lane = t0 & 63, wave = t0 >> 6;
  const int wr = wave >> 1, wc = wave & 1;
  const int row0 = by * 128, col0 = bx * 128;
  const int lrow = lane & 15, lkg = lane >> 4;

  const int lp = lane ^ ((lane >> 3) & 3);
  const int srow_off = lp >> 2;
  const int skel = (lp & 3) * 8;
  const int c0 = wave * 2, c1 = c0 + 1;
  const int arow_c0 = row0 + c0 * 16 + srow_off;
  const int arow_c1 = row0 + c1 * 16 + srow_off;
  int brow_c0 = col0 + c0 * 16 + srow_off; if (brow_c0 > N - 1) brow_c0 = N - 1;
  int brow_c1 = col0 + c1 * 16 + srow_off; if (brow_c1 > N - 1) brow_c1 = N - 1;

  int aoff[4], boff[4];
#pragma unroll
  for (int m = 0; m < 4; ++m) {
    int r = wr * 64 + m * 16 + lrow;
    int off = r * 32 + lkg * 8;
    aoff[m] = off ^ ((off >> 3) & 0x18);
    r = wc * 64 + m * 16 + lrow;
    off = r * 32 + lkg * 8;
    boff[m] = off ^ ((off >> 3) & 0x18);
  }

  const int NT = K >> 5;

#pragma unroll
  for (int pt = 0; pt < 3; ++pt) {
    u16* ab = &S[pt * 8192];
    const int kb = pt * 32 + skel;
    gload16(A  + (size_t)arow_c0 * K + kb, ab + c0 * 512);
    gload16(A  + (size_t)arow_c1 * K + kb, ab + c1 * 512);
    gload16(BT + (size_t)brow_c0 * K + kb, ab + 4096 + c0 * 512);
    gload16(BT + (size_t)brow_c1 * K + kb, ab + 4096 + c1 * 512);
  }

  f32x4 acc[4][4];
#pragma unroll
  for (int m = 0; m < 4; ++m)
#pragma unroll
    for (int n = 0; n < 4; ++n) acc[m][n] = 0.f;

  for (int t = 0; t < NT; ++t) {
    if (t + 2 < NT)      asm volatile("s_waitcnt vmcnt(8)" ::: "memory");
    else if (t + 1 < NT) asm volatile("s_waitcnt vmcnt(4)" ::: "memory");
    else                 asm volatile("s_waitcnt vmcnt(0)" ::: "memory");
    __builtin_amdgcn_s_barrier();
    __builtin_amdgcn_sched_barrier(0);

    const u16* ab = &S[(t & 3) * 8192];
    bf16x8 af[4], bb[4];
#pragma unroll
    for (int m = 0; m < 4; ++m)
      af[m] = *reinterpret_cast<const bf16x8*>(ab + aoff[m]);
#pragma unroll
    for (int n = 0; n < 4; ++n)
      bb[n] = *reinterpret_cast<const bf16x8*>(ab + 4096 + boff[n]);

    if (t + 3 < NT) {
      u16* sb = &S[((t + 3) & 3) * 8192];
      const int kb = (t + 3) * 32 + skel;
      gload16(A  + (size_t)arow_c0 * K + kb, sb + c0 * 512);
      gload16(A  + (size_t)arow_c1 * K + kb, sb + c1 * 512);
      gload16(BT + (size_t)brow_c0 * K + kb, sb + 4096 + c0 * 512);
      gload16(BT + (size_t)brow_c1 * K + kb, sb + 4096 + c1 * 512);
    }

    __builtin_amdgcn_s_setprio(1);
#pragma unroll
    for (int m = 0; m < 4; ++m)
#pragma unroll
      for (int n = 0; n < 4; ++n)
        acc[m][n] = __builtin_amdgcn_mfma_f32_16x16x32_bf16(af[m], bb[n], acc[m][n], 0, 0, 0);
    __builtin_amdgcn_s_setprio(0);
  }

#pragma unroll
  for (int m = 0; m < 4; ++m) {
#pragma unroll
    for (int n = 0; n < 4; ++n) {
      int col = col0 + wc * 64 + n * 16 + lrow;
      int row = row0 + wr * 64 + m * 16 + lkg * 4;
      if (col < N) {
#pragma unroll
        for (int i = 0; i < 4; ++i) {
          size_t idx = (size_t)(row + i) * N + col;
          if (EPI == 1) ((u16*)Cv)[idx] = f2bf(acc[m][n][i]);
          else          ((float*)Cv)[idx] = acc[m][n][i];
        }
      }
    }
  }
}

template <int EPI>
__global__ __launch_bounds__(256) void gemm_v3_kernel(const u16* __restrict__ A,
                                                      const u16* __restrict__ BT,
                                                      void* __restrict__ Cv,
                                                      void* __restrict__ Cv2,
                                                      int M, int N, int K) {
  __shared__ __align__(16) u16 S[4 * 8192];
  gemm_v3_body<EPI>(A, BT, Cv, Cv2, M, N, K, blockIdx.x, blockIdx.y, S);
}

// ---------------- GEMM v4 body: 128(M)x256(N) tile, per-wave 64x128 ----------------
template <int EPI>
__device__ __forceinline__ void gemm_v4_body(const u16* __restrict__ A,
                                             const u16* __restrict__ BT,
                                             void* __restrict__ Cv,
                                             void* __restrict__ Cv2,
                                             int M, int N, int K,
                                             int bx, int by, u16* S) {
  const int t0 = threadIdx.x;
  const int lane = t0 & 63, wave = t0 >> 6;
  const int wr = wave >> 1, wc = wave & 1;
  const int row0 = by * 128, col0 = bx * 256;
  const int lrow = lane & 15, lkg = lane >> 4;

  const int lp = lane ^ ((lane >> 3) & 3);
  const int srow_off = lp >> 2;
  const int skel = (lp & 3) * 8;

  const int ac0 = wave * 2, ac1 = ac0 + 1;
  const int arow_0 = row0 + ac0 * 16 + srow_off;
  const int arow_1 = row0 + ac1 * 16 + srow_off;
  int brow[4];
#pragma unroll
  for (int j = 0; j < 4; ++j) {
    int r = col0 + (wave * 4 + j) * 16 + srow_off;
    brow[j] = (r > N - 1) ? (N - 1) : r;
  }

  int aoff[4], boff[8];
#pragma unroll
  for (int m = 0; m < 4; ++m) {
    int r = wr * 64 + m * 16 + lrow;
    int off = r * 32 + lkg * 8;
    aoff[m] = off ^ ((off >> 3) & 0x18);
  }
#pragma unroll
  for (int n = 0; n < 8; ++n) {
    int r = wc * 128 + n * 16 + lrow;
    int off = r * 32 + lkg * 8;
    boff[n] = off ^ ((off >> 3) & 0x18);
  }

  const int NT = K >> 5;

#pragma unroll
  for (int pt = 0; pt < 2; ++pt) {
    u16* sb = &S[pt * 12288];
    const int kb = pt * 32 + skel;
    gload16(A + (size_t)arow_0 * K + kb, sb + ac0 * 512);
    gload16(A + (size_t)arow_1 * K + kb, sb + ac1 * 512);
#pragma unroll
    for (int j = 0; j < 4; ++j)
      gload16(BT + (size_t)brow[j] * K + kb, sb + 4096 + (wave * 4 + j) * 512);
  }

  f32x4 acc[4][8];
#pragma unroll
  for (int m = 0; m < 4; ++m)
#pragma unroll
    for (int n = 0; n < 8; ++n) acc[m][n] = 0.f;

  int bufr = 0, bufw = 2;
  for (int t = 0; t < NT; ++t) {
    if (t + 2 < NT) {
      u16* sb = &S[bufw * 12288];
      const int kb = (t + 2) * 32 + skel;
      gload16(A + (size_t)arow_0 * K + kb, sb + ac0 * 512);
      gload16(A + (size_t)arow_1 * K + kb, sb + ac1 * 512);
#pragma unroll
      for (int j = 0; j < 4; ++j)
        gload16(BT + (size_t)brow[j] * K + kb, sb + 4096 + (wave * 4 + j) * 512);
      bufw = (bufw + 1 == 3) ? 0 : bufw + 1;
      asm volatile("s_waitcnt vmcnt(12)" ::: "memory");
    } else if (t + 1 < NT) {
      asm volatile("s_waitcnt vmcnt(6)" ::: "memory");
    } else {
      asm volatile("s_waitcnt vmcnt(0)" ::: "memory");
    }
    __builtin_amdgcn_s_barrier();
    __builtin_amdgcn_sched_barrier(0);

    const u16* ab = &S[bufr * 12288];
    bufr = (bufr + 1 == 3) ? 0 : bufr + 1;
    bf16x8 af[4];
#pragma unroll
    for (int m = 0; m < 4; ++m)
      af[m] = *reinterpret_cast<const bf16x8*>(ab + aoff[m]);

    __builtin_amdgcn_s_setprio(1);
#pragma unroll
    for (int n = 0; n < 8; ++n) {
      bf16x8 bbn = *reinterpret_cast<const bf16x8*>(ab + 4096 + boff[n]);
#pragma unroll
      for (int m = 0; m < 4; ++m)
        acc[m][n] = __builtin_amdgcn_mfma_f32_16x16x32_bf16(af[m], bbn, acc[m][n], 0, 0, 0);
    }
    __builtin_amdgcn_s_setprio(0);
  }

#pragma unroll
  for (int m = 0; m < 4; ++m) {
#pragma unroll
    for (int n = 0; n < 8; ++n) {
      int col = col0 + wc * 128 + n * 16 + lrow;
      int row = row0 + wr * 64 + m * 16 + lkg * 4;
      if (EPI == 2) {
        int d = col & 255, hh = col >> 8;
        if (d < 128) {
          u16* dst = (u16*)Cv + ((size_t)hh * 2048 + row) * 192 + d;
#pragma unroll
          for (int i = 0; i < 4; ++i) dst[(size_t)i * 192] = f2bf(acc[m][n][i]);
        } else {
          s16x4 v;
#pragma unroll
          for (int i = 0; i < 4; ++i) v[i] = (short)f2bf(acc[m][n][i]);
          *reinterpret_cast<s16x4*>((u16*)Cv2 + ((size_t)hh * 128 + (d - 128)) * 2048 + row) = v;
        }
      } else if (col < N) {
#pragma unroll
        for (int i = 0; i < 4; ++i) {
          size_t idx = (size_t)(row + i) * N + col;
          if (EPI == 1) ((u16*)Cv)[idx] = f2bf(acc[m][n][i]);
          else          ((float*)Cv)[idx] = acc[m][n][i];
        }
      }
    }
  }
}

template <int EPI>
__global__ __launch_bounds__(256, 2) void gemm_v4_kernel(const u16* __restrict__ A,
                                                         const u16* __restrict__ BT,
                                                         void* __restrict__ Cv,
                                                         void* __restrict__ Cv2,
                                                         int M, int N, int K) {
  __shared__ __align__(16) u16 S[3 * 12288];
  gemm_v4_body<EPI>(A, BT, Cv, Cv2, M, N, K, blockIdx.x, blockIdx.y, S);
}

__global__ __launch_bounds__(256, 2) void gemm_qkv_kernel(const u16* __restrict__ qan,
                                                          const u16* __restrict__ WqbT,
                                                          u16* __restrict__ qout,
                                                          const u16* __restrict__ cn,
                                                          const u16* __restrict__ WkvbT,
                                                          u16* __restrict__ kfb,
                                                          u16* __restrict__ vTb) {
  __shared__ __align__(16) u16 S[3 * 12288];
  if (blockIdx.z == 0) {
    if (blockIdx.x >= 24) return;
    gemm_v4_body<1>(qan, WqbT, qout, nullptr, 2048, 6144, 1536, blockIdx.x, blockIdx.y, S);
  } else {
    gemm_v4_body<2>(cn, WkvbT, kfb, vTb, 2048, 8192, 512, blockIdx.x, blockIdx.y, S);
  }
}

// ---------------- causal flash attention v7: KVBLK=64, K dbuf + counted vmcnt, V post-PV ----------------
__global__ __launch_bounds__(256) void mla_attn_kernel(const u16* __restrict__ qf,
                                                       const u16* __restrict__ kf,
                                                       const u16* __restrict__ vT,
                                                       u16* __restrict__ o) {
  const int h = blockIdx.x, pair = blockIdx.y;
  const int t = threadIdx.x, wave = t >> 6, lane = t & 63;
  const int lrow = lane & 15, lkg = lane >> 4;
  __shared__ __align__(16) u16 Kt[2][24 * 512];
  __shared__ __align__(16) u16 Vt[16 * 512];
  __shared__ __align__(16) u16 Pl[4][16][72];

  const u16* ksrc0 = kf + ((size_t)h * 2048 + wave * 16 + lrow) * 192 + lkg * 8;
  const u16* vsrc0 = vT + ((size_t)h * 128 + wave * 32 + lrow) * 2048 + lkg * 8;

  for (int qq = 0; qq < 2; ++qq) {
    const int qb = qq ? (31 - pair) : pair;
    const int qbase = qb * 64 + wave * 16;

    bf16x8 qfr[6];
    const u16* qrow_ptr = qf + ((size_t)h * 2048 + qbase + lrow) * 192;
#pragma unroll
    for (int kk = 0; kk < 6; ++kk)
      qfr[kk] = *reinterpret_cast<const bf16x8*>(qrow_ptr + kk * 32 + lkg * 8);

    f32x4 acc_o[8];
#pragma unroll
    for (int f = 0; f < 8; ++f) acc_o[f] = 0.f;
    float m_run[4], l_par[4];
#pragma unroll
    for (int i = 0; i < 4; ++i) { m_run[i] = -1e30f; l_par[i] = 0.f; }

    const int nt = qb + 1;   // KV tiles of 64

    // prologue: K(0) -> Kt[0], V(0) -> Vt
#pragma unroll
    for (int kk = 0; kk < 6; ++kk)
      gload16(ksrc0 + kk * 32, &Kt[0][(wave * 6 + kk) * 512]);
#pragma unroll
    for (int j = 0; j < 4; ++j) {
      int fo = (j >> 1), ck = j & 1;
      gload16(vsrc0 + (size_t)fo * 16 * 2048 + ck * 32,
              &Vt[((wave * 2 + fo) * 2 + ck) * 512]);
    }

    for (int it = 0; it < nt; ++it) {
      const int kt = it * 64;
      if (it + 1 < nt) {
        const u16* ks = ksrc0 + (size_t)(kt + 64) * 192;
        u16* kd = &Kt[(it + 1) & 1][0];
#pragma unroll
        for (int kk = 0; kk < 6; ++kk)
          gload16(ks + kk * 32, kd + (wave * 6 + kk) * 512);
        asm volatile("s_waitcnt vmcnt(6)" ::: "memory");
      } else {
        asm volatile("s_waitcnt vmcnt(0)" ::: "memory");
      }
      __builtin_amdgcn_s_barrier();
      __builtin_amdgcn_sched_barrier(0);

      const u16* Kb = &Kt[it & 1][0];
      f32x4 sv[4];
#pragma unroll
      for (int cg = 0; cg < 4; ++cg) sv[cg] = 0.f;
#pragma unroll
      for (int cg = 0; cg < 4; ++cg)
#pragma unroll
        for (int kk = 0; kk < 6; ++kk) {
          bf16x8 kfr = *reinterpret_cast<const bf16x8*>(&Kb[(cg * 6 + kk) * 512 + lane * 8]);
          sv[cg] = __builtin_amdgcn_mfma_f32_16x16x32_bf16(qfr[kk], kfr, sv[cg], 0, 0, 0);
        }

      const int qrow_b = qbase + lkg * 4;
      if (it + 1 == nt) {
#pragma unroll
        for (int cg = 0; cg < 4; ++cg) {
          int kvcol = kt + cg * 16 + lrow;
#pragma unroll
          for (int i = 0; i < 4; ++i)
            if (kvcol > qrow_b + i) sv[cg][i] = -__builtin_inff();
        }
      }
      float tmax[4];
#pragma unroll
      for (int i = 0; i < 4; ++i)
        tmax[i] = fmaxf(fmaxf(sv[0][i], sv[1][i]), fmaxf(sv[2][i], sv[3][i]));
#pragma unroll
      for (int m = 8; m >= 1; m >>= 1)
#pragma unroll
        for (int i = 0; i < 4; ++i) tmax[i] = fmaxf(tmax[i], __shfl_xor(tmax[i], m));
      int need = 0;
#pragma unroll
      for (int i = 0; i < 4; ++i) need |= (tmax[i] > m_run[i] + 8.f) ? 1 : 0;
      if (__any(need)) {
#pragma unroll
        for (int i = 0; i < 4; ++i) {
          float mnew = fmaxf(m_run[i], tmax[i]);
          float alpha = __expf(m_run[i] - mnew);
          m_run[i] = mnew;
          l_par[i] *= alpha;
#pragma unroll
          for (int f = 0; f < 8; ++f) acc_o[f][i] *= alpha;
        }
      }
#pragma unroll
      for (int i = 0; i < 4; ++i) {
#pragma unroll
        for (int cg = 0; cg < 4; ++cg) sv[cg][i] = __expf(sv[cg][i] - m_run[i]);
        l_par[i] += (sv[0][i] + sv[1][i]) + (sv[2][i] + sv[3][i]);
      }
#pragma unroll
      for (int cg = 0; cg < 4; ++cg)
#pragma unroll
        for (int i = 0; i < 4; ++i)
          Pl[wave][lkg * 4 + i][cg * 16 + lrow] = f2bf(sv[cg][i]);
#pragma unroll
      for (int ck = 0; ck < 2; ++ck) {
        bf16x8 pf = *reinterpret_cast<const bf16x8*>(&Pl[wave][lrow][ck * 32 + lkg * 8]);
#pragma unroll
        for (int f = 0; f < 8; ++f) {
          bf16x8 vfr = *reinterpret_cast<const bf16x8*>(&Vt[(f * 2 + ck) * 512 + lane * 8]);
          acc_o[f] = __builtin_amdgcn_mfma_f32_16x16x32_bf16(pf, vfr, acc_o[f], 0, 0, 0);
        }
      }
      __builtin_amdgcn_sched_barrier(0);
      __builtin_amdgcn_s_barrier();
      if (it + 1 < nt) {
        const u16* vs = vsrc0 + kt + 64;
#pragma unroll
        for (int j = 0; j < 4; ++j) {
          int fo = (j >> 1), ck = j & 1;
          gload16(vs + (size_t)fo * 16 * 2048 + ck * 32,
                  &Vt[((wave * 2 + fo) * 2 + ck) * 512]);
        }
      }
    }
#pragma unroll
    for (int i = 0; i < 4; ++i)
#pragma unroll
      for (int m = 8; m >= 1; m >>= 1) l_par[i] += __shfl_xor(l_par[i], m);
#pragma unroll
    for (int f = 0; f < 8; ++f)
#pragma unroll
      for (int i = 0; i < 4; ++i) {
        int row = qbase + lkg * 4 + i;
        int col = h * 128 + f * 16 + lrow;
        o[(size_t)row * 4096 + col] = f2bf(acc_o[f][i] / l_par[i]);
      }
  }
}

// ---------------------------------------------------------------
extern "C" void kernel_launch(void* const* d_in, const int* in_sizes, int n_in,
                              void* d_out, int out_size, void* d_ws, size_t ws_size,
                              hipStream_t stream) {
  (void)in_sizes; (void)n_in; (void)out_size; (void)ws_size;
  const float* hs   = (const float*)d_in[0];
  const float* Wqa  = (const float*)d_in[1];
  const float* qln  = (const float*)d_in[2];
  const float* Wqb  = (const float*)d_in[3];
  const float* Wkva = (const float*)d_in[4];
  const float* kvln = (const float*)d_in[5];
  const float* Wkvb = (const float*)d_in[6];
  const float* Wo   = (const float*)d_in[7];
  float* out = (float*)d_out;

  char* p = (char*)d_ws;
  size_t off = 0;
  auto carve = [&](size_t bytes) {
    char* r = p + off;
    off += (bytes + 255) & ~(size_t)255;
    return r;
  };
  u16* hs_bf = (u16*)carve((size_t)2048 * 4096 * 2);
  u16* WabT  = (u16*)carve((size_t)2112 * 4096 * 2);   // [0..1535]=WqaT, [1536..2111]=WkvaT
  u16* WqbT  = (u16*)carve((size_t)6144 * 1536 * 2);
  u16* WkvbT = (u16*)carve((size_t)8192 * 512 * 2);
  u16* WoT   = (u16*)carve((size_t)4096 * 4096 * 2);
  u16* fused = (u16*)carve((size_t)2048 * 2112 * 2);   // [qa | ckv] per row
  u16* qan   = (u16*)carve((size_t)2048 * 1536 * 2);
  u16* q     = (u16*)carve((size_t)2048 * 6144 * 2);
  u16* cn    = (u16*)carve((size_t)2048 * 512 * 2);
  u16* qfb   = (u16*)carve((size_t)32 * 2048 * 192 * 2);
  u16* kfb   = (u16*)carve((size_t)32 * 2048 * 192 * 2);
  u16* vTb   = (u16*)carve((size_t)32 * 128 * 2048 * 2);
  u16* ob    = (u16*)carve((size_t)2048 * 4096 * 2);
  float* cost = (float*)carve((size_t)65536 * 4);
  float* sint = (float*)carve((size_t)65536 * 4);

  // --- merged prep: cast + 5 transposes + rope table (1 launch) ---
  prep_merged_kernel<<<17984, 256, 0, stream>>>(hs, hs_bf, Wqa, Wkva, WabT,
                                                Wqb, WqbT, Wkvb, WkvbT, Wo, WoT,
                                                cost, sint);

  // --- fused first-stage GEMM (ragged N=2112 -> v3) ---
  gemm_v3_kernel<1><<<dim3(17, 16), 256, 0, stream>>>(hs_bf, WabT, fused, nullptr, 2048, 2112, 4096);

  // --- merged norms (1 launch) ---
  norms_merged_kernel<<<4096, 256, 0, stream>>>(fused, qln, kvln, qan, cn);

  // --- merged q+kv second-stage GEMMs (v4 tiles; exact-fit N) ---
  gemm_qkv_kernel<<<dim3(32, 16, 2), 256, 0, stream>>>(qan, WqbT, q, cn, WkvbT, kfb, vTb);

  // --- merged builds: qf RoPE+scale, kf RoPE (1 launch) ---
  builds_merged_kernel<<<8192, 256, 0, stream>>>(q, fused + 1536, cost, sint, qfb, kfb);

  // --- attention v7 (512 blocks, 2/CU, KVBLK=64, K dbuf + counted vmcnt) ---
  mla_attn_kernel<<<dim3(32, 16), 256, 0, stream>>>(qfb, kfb, vTb, ob);

  // --- output projection (v4: 16x16 = 256 blocks, exact 1/CU) ---
  gemm_v4_kernel<0><<<dim3(16, 16), 256, 0, stream>>>(ob, WoT, out, nullptr, 2048, 4096, 4096);
}